// Round 1
// baseline (121.822 us; speedup 1.0000x reference)
//
#include <hip/hip_runtime.h>
#include <hip/hip_bf16.h>

#define NHEAD 4
#define FIN   768
#define FOUT  64
#define BSZ   4
#define NSEQ  2048
#define BH    (BSZ*NHEAD)
#define LOG2E 1.44269504088896f

typedef __attribute__((ext_vector_type(8)))  short bf16x8;   // MFMA A/B frag
typedef __attribute__((ext_vector_type(16))) float f32x16;   // MFMA 32x32 C/D
typedef __attribute__((ext_vector_type(8)))  unsigned short u16x8;
typedef __attribute__((ext_vector_type(4)))  unsigned short u16x4;
typedef __attribute__((ext_vector_type(4)))  unsigned u32x4;

__device__ __forceinline__ unsigned short f2bf(float f){
  unsigned b = __float_as_uint(f);
  return (unsigned short)((b + 0x7fffu + ((b >> 16) & 1u)) >> 16);
}
__device__ __forceinline__ float fexp2(float x){
#if __has_builtin(__builtin_amdgcn_exp2f)
  return __builtin_amdgcn_exp2f(x);
#else
  return exp2f(x);
#endif
}
__device__ __forceinline__ unsigned pkbf(float lo, float hi){
#if __has_builtin(__builtin_amdgcn_cvt_pk_bf16_f32)
  typedef __attribute__((ext_vector_type(2))) __bf16 bf2;
  union { bf2 v; unsigned u; } cv;
  cv.v = __builtin_amdgcn_cvt_pk_bf16_f32(lo, hi);
  return cv.u;
#else
  return (unsigned)f2bf(lo) | ((unsigned)f2bf(hi) << 16);
#endif
}
// fast tanh via exp2: tanh(v) = 1 - 2/(exp2(2*log2e*v)+1). |err| ~1e-7, safe
// for |v|<~40 (h' bounded ~|8| here); large |v| saturates correctly to +-1.
__device__ __forceinline__ float fast_tanh(float v){
  const float e = fexp2(v * (2.0f*LOG2E));
#if __has_builtin(__builtin_amdgcn_rcpf)
  return 1.0f - 2.0f*__builtin_amdgcn_rcpf(e + 1.0f);
#else
  return 1.0f - 2.0f/(e + 1.0f);
#endif
}
// async global->LDS, 16B per lane. LDS dest is wave-uniform base + lane*16.
__device__ __forceinline__ void gll16(const void* g, void* l){
  __builtin_amdgcn_global_load_lds(
      (const __attribute__((address_space(1))) unsigned*)g,
      (__attribute__((address_space(3))) unsigned*)l, 16, 0, 0);
}

// ---------------------------------------------------------------------------
// Kernel P: one-time fp32->bf16 conversion of h and w into PRE-SWIZZLED image
// layouts, so k_hprime can stage with linear-dest global_load_lds and the
// unchanged XOR-swizzled MFMA reads see the right bytes.
//
// Image spec (matches k_hprime's reader, derived from the proven r9 staging):
//   16B unit (row, it, p):  p in [0,16), half hf=p>>3, stored-chunk cs=p&7
//   contains k = it*128 + hf*64 + ((cs ^ (row&7))*8 + j, j=0..7, as bf16.
// h_bf: [row 8192][it 6][p 16] units  (12.58 MB), row = b*2048+n
// w_bf: [head 4][it 6][o 64][p 16] units (384 KB)
// ---------------------------------------------------------------------------
__global__ __launch_bounds__(512) void k_prep(
    const float* __restrict__ h, const float* __restrict__ w,
    unsigned short* __restrict__ h_bf, unsigned short* __restrict__ w_bf)
{
  const int tid = threadIdx.x;
  const int bid = blockIdx.x;
  if (bid < 1536){                       // h part: 1536*512 = 786432 units
    const int gid = bid*512 + tid;
    const int row = gid / 96;
    const int rem = gid - row*96;
    const int it  = rem >> 4, p = rem & 15;
    const float* src = h + (size_t)row*FIN + it*128 + ((p>>3)<<6)
                         + (((p & 7) ^ (row & 7)) << 3);
    const float4 a = *(const float4*)src;
    const float4 b = *(const float4*)(src + 4);
    u32x4 pk;
    pk[0] = pkbf(a.x, a.y); pk[1] = pkbf(a.z, a.w);
    pk[2] = pkbf(b.x, b.y); pk[3] = pkbf(b.z, b.w);
    *(u32x4*)((char*)h_bf + (size_t)gid*16) = pk;   // perfectly coalesced
  } else {                               // w part: 48*512 = 24576 units
    const int wid = (bid - 1536)*512 + tid;
    const int p   = wid & 15, o = (wid >> 4) & 63, hi6 = wid >> 10;
    const int head = hi6 / 6, it = hi6 - head*6;
    const int k0 = it*128 + ((p>>3)<<6) + (((p & 7) ^ (o & 7)) << 3);
    const float* sw = w + (size_t)head*FIN*FOUT + (size_t)k0*FOUT + o;
    float r0 = sw[0*FOUT], r1 = sw[1*FOUT], r2 = sw[2*FOUT], r3 = sw[3*FOUT];
    float r4 = sw[4*FOUT], r5 = sw[5*FOUT], r6 = sw[6*FOUT], r7 = sw[7*FOUT];
    u32x4 pk;
    pk[0] = pkbf(r0, r1); pk[1] = pkbf(r2, r3);
    pk[2] = pkbf(r4, r5); pk[3] = pkbf(r6, r7);
    *(u32x4*)((char*)w_bf + (size_t)wid*16) = pk;
  }
}

// ---------------------------------------------------------------------------
// Kernel A: h' = h @ w_head via 32x32x16 MFMA. Staging is now pure
// global_load_lds from the pre-swizzled bf16 images: 4 x 16B issues per
// thread per K-iter, zero staging VALU/VGPR. Double-buffered, one barrier
// per iter. 2 blocks/CU (all 512 blocks resident, single round).
// XCD swizzle unchanged: bh1 keeps one head's w L2-resident per XCD.
// ---------------------------------------------------------------------------
__global__ __launch_bounds__(512, 4) void k_hprime(
    const unsigned short* __restrict__ h_bf, const unsigned short* __restrict__ w_bf,
    const float* __restrict__ a_src, const float* __restrict__ a_dst,
    unsigned short* __restrict__ hpz2, float* __restrict__ srcv,
    float* __restrict__ dstv)
{
  __shared__ __align__(16) char smem[65536];
  // A0@0, A1@16384, B0@32768, B1@49152
  // epilogue overlays: scratch@0 (16K), psumS@16384, psumD@16896, Tt@32768 (8K)
  float* psumS = (float*)(smem + 16384);
  float* psumD = (float*)(smem + 16896);
  char*  Tt    = smem + 32768;

  const int tid  = threadIdx.x;
  const int bid  = blockIdx.x;
  const int bh1  = (bid & 7) | (((bid >> 3) & 1) << 3);
  const int head = bh1 & 3;
  const int jbase = (bid >> 4) << 6;                 // within-sequence row base
  const int i0a   = (bh1 >> 2)*NSEQ + jbase;         // global flat row
  const int wave = tid >> 6, lane = tid & 63;
  const int wm = wave & 1, wn = (wave >> 1) & 1, kw = wave >> 2;
  const int l32 = lane & 31, h32 = lane >> 5;

  f32x16 acc = {0,0,0,0,0,0,0,0,0,0,0,0,0,0,0,0};

  // staging geometry: LDS flat = wave*1024 + lane*16 (+ q*8192)
  //   -> image row = wave*4 + (lane>>4) + q*32, p = lane&15
  const int rowL = wave*4 + (lane >> 4);
  const int p16  = lane & 15;
  const char* sA = (const char*)h_bf + ((size_t)(i0a + rowL)*96 + p16)*16;
  const char* sB = (const char*)w_bf + (size_t)(head*6)*16384 + rowL*256 + p16*16;

  // prologue: it=0 -> buf0
  {
    char* AbW = smem +         wave*1024;
    char* BbW = smem + 32768 + wave*1024;
    gll16(sA,         AbW);          // A rows 0..31
    gll16(sA + 49152, AbW + 8192);   // A rows 32..63 (+32*1536 B in h_bf)
    gll16(sB,         BbW);          // B o 0..31
    gll16(sB + 8192,  BbW + 8192);   // B o 32..63 (+32*256 B in w_bf)
  }
  __syncthreads();

  for (int it = 0; it < 6; ++it){
    const int bb = it & 1;
    char* Ab = smem +         bb*16384;
    char* Bb = smem + 32768 + bb*16384;
    if (it < 5){
      char* AbW = smem +         (bb^1)*16384 + wave*1024;
      char* BbW = smem + 32768 + (bb^1)*16384 + wave*1024;
      const char* sAi = sA + (size_t)(it+1)*256;
      const char* sBi = sB + (size_t)(it+1)*16384;
      gll16(sAi,         AbW);
      gll16(sAi + 49152, AbW + 8192);
      gll16(sBi,         BbW);
      gll16(sBi + 8192,  BbW + 8192);
    }
    #pragma unroll
    for (int s = 0; s < 4; ++s){
      const int slot = (((s*2 + h32) ^ (l32 & 7)) << 4);
      bf16x8 av = *(const bf16x8*)(Ab + (wm*32 + l32)*256 + kw*128 + slot);
      bf16x8 bv = *(const bf16x8*)(Bb + (wn*32 + l32)*256 + kw*128 + slot);
      acc = __builtin_amdgcn_mfma_f32_32x32x16_bf16(av, bv, acc, 0, 0, 0);
    }
    __syncthreads();                     // drains prefetch; next buf ready
  }

  // kw-merge via scratch@0 (A0 region; disjoint from iter-5's A1/B1 reads)
  if (kw == 1) *(f32x16*)(smem + (size_t)((wave & 3)*64 + lane)*64) = acc;
  __syncthreads();
  if (kw == 0){
    acc += *(const f32x16*)(smem + (size_t)((wave & 3)*64 + lane)*64);
    const float as = a_src[head*64 + wn*32 + l32];
    const float ad = a_dst[head*64 + wn*32 + l32];
    #pragma unroll
    for (int rb2 = 0; rb2 < 4; ++rb2){
      const int jb = wm*32 + rb2*8 + h32*4;
      u16x4 c4;
      #pragma unroll
      for (int q = 0; q < 4; ++q){
        const float v = acc[rb2*4 + q];
        c4[q] = f2bf(v);
        const float t = fast_tanh(v);
        float ps = t*as, pd = t*ad;
        ps += __shfl_xor(ps, 1);  ps += __shfl_xor(ps, 2);  ps += __shfl_xor(ps, 4);
        ps += __shfl_xor(ps, 8);  ps += __shfl_xor(ps, 16);
        pd += __shfl_xor(pd, 1);  pd += __shfl_xor(pd, 2);  pd += __shfl_xor(pd, 4);
        pd += __shfl_xor(pd, 8);  pd += __shfl_xor(pd, 16);
        if (l32 == 0){
          psumS[(jb + q)*2 + wn] = ps;
          psumD[(jb + q)*2 + wn] = pd;
        }
      }
      const int orow = wn*32 + l32;
      const int slot = ((jb >> 3) & 7) ^ (orow & 7);
      *(u16x4*)(Tt + orow*128 + slot*16 + (jb & 7)*2) = c4;
    }
  }
  __syncthreads();

  {
    const int o = tid & 63, c = tid >> 6;
    u16x8 val = *(const u16x8*)(Tt + o*128 + ((c ^ (o & 7)) << 4));
    *(u16x8*)((char*)hpz2 + ((size_t)(bh1*256 + (jbase >> 3) + c)*64 + o)*16) = val;
  }
  if (tid < 64){
    // log2-domain pre-scale; NO max subtraction needed downstream (bounded
    // inputs: |s|,|d| <= ~28.1 in log2 units -> exp2 range fp32-safe)
    srcv[(size_t)bh1*NSEQ + jbase + tid] = (psumS[tid*2] + psumS[tid*2 + 1]) * LOG2E;
    dstv[(size_t)bh1*NSEQ + jbase + tid] = (psumD[tid*2] + psumD[tid*2 + 1]) * LOG2E;
  }
}

// ---------------------------------------------------------------------------
// Kernel B: register-direct P, linear H staging, NO softmax-max (scale-
// invariant: p = exp2(lrelu(s+d)), l = sum p, out = acc/l).  UNCHANGED.
// ---------------------------------------------------------------------------
__global__ __launch_bounds__(512, 4) void k_attn(
    const unsigned short* __restrict__ hpz2, const float* __restrict__ srcv,
    const float* __restrict__ dstv, const float* __restrict__ bias,
    float* __restrict__ out)
{
  __shared__ __align__(16) char smem[33792];   // H0@0, H1@16384, Lbuf@32768
  float* Lbuf = (float*)(smem + 32768);        // [8][32]

  const int tid = threadIdx.x;
  const int bid = blockIdx.x;
  const int bh  = (bid & 7) | (((bid >> 3) & 1) << 3);
  const int i0  = (bid >> 4) << 6;
  const int wave = tid >> 6, lane = tid & 63;
  const int wm = wave & 1, jw = wave >> 1;
  const int l32 = lane & 31, h32 = lane >> 5;

  const float s2 = srcv[(size_t)bh*NSEQ + i0 + wm*32 + l32];
  const float u_ = s2;                 // lrelu(s+d) = max(u_+d, 0.2d+v_)
  const float v_ = 0.2f*s2;
  const float* dptr = dstv + (size_t)bh*NSEQ;

  const u16x8* gp = (const u16x8*)((const char*)hpz2 + (size_t)bh*256*64*16);

  f32x16 accO0 = {0,0,0,0,0,0,0,0,0,0,0,0,0,0,0,0};
  f32x16 accO1 = {0,0,0,0,0,0,0,0,0,0,0,0,0,0,0,0};
  float lpart = 0.f;

  *(u16x8*)(smem + tid*16)         = gp[tid];
  *(u16x8*)(smem + (tid + 512)*16) = gp[tid + 512];
  __syncthreads();

  for (int w = 0; w < 16; ++w){
    char* cur = smem + (w & 1)*16384;
    char* nxt = smem + ((w + 1) & 1)*16384;
    u16x8 r0, r1;
    if (w < 15){
      r0 = gp[(w+1)*1024 + tid];
      r1 = gp[(w+1)*1024 + tid + 512];
    }
    #pragma unroll
    for (int stl = 0; stl < 2; ++stl){
      const int Jl = jw*4 + stl*2 + h32;
      const int j0 = (w*16 + Jl)*8;
      float4 d0 = *(const float4*)(dptr + j0);
      float4 d1 = *(const float4*)(dptr + j0 + 4);
      float e0,e1,e2,e3,e4,e5,e6,e7;
      e0 = fexp2(fmaxf(u_ + d0.x, fmaf(0.2f, d0.x, v_)));
      e1 = fexp2(fmaxf(u_ + d0.y, fmaf(0.2f, d0.y, v_)));
      e2 = fexp2(fmaxf(u_ + d0.z, fmaf(0.2f, d0.z, v_)));
      e3 = fexp2(fmaxf(u_ + d0.w, fmaf(0.2f, d0.w, v_)));
      e4 = fexp2(fmaxf(u_ + d1.x, fmaf(0.2f, d1.x, v_)));
      e5 = fexp2(fmaxf(u_ + d1.y, fmaf(0.2f, d1.y, v_)));
      e6 = fexp2(fmaxf(u_ + d1.z, fmaf(0.2f, d1.z, v_)));
      e7 = fexp2(fmaxf(u_ + d1.w, fmaf(0.2f, d1.w, v_)));
      lpart += ((e0+e1)+(e2+e3)) + ((e4+e5)+(e6+e7));
      u32x4 pk;
      pk[0] = pkbf(e0, e1); pk[1] = pkbf(e2, e3);
      pk[2] = pkbf(e4, e5); pk[3] = pkbf(e6, e7);
      const bf16x8 pA = __builtin_bit_cast(bf16x8, pk);
      const bf16x8 bv0 = *(const bf16x8*)(cur + (Jl*64 +      l32)*16);
      const bf16x8 bv1 = *(const bf16x8*)(cur + (Jl*64 + 32 + l32)*16);
      accO0 = __builtin_amdgcn_mfma_f32_32x32x16_bf16(pA, bv0, accO0, 0, 0, 0);
      accO1 = __builtin_amdgcn_mfma_f32_32x32x16_bf16(pA, bv1, accO1, 0, 0, 0);
    }
    if (w < 15){
      *(u16x8*)(nxt + tid*16)         = r0;
      *(u16x8*)(nxt + (tid + 512)*16) = r1;
    }
    __syncthreads();
  }

  lpart += __shfl_xor(lpart, 32);
  if (lane < 32) Lbuf[(wm*4 + jw)*32 + l32] = lpart;

  const float4 bia = *(const float4*)(bias + (tid & 15)*4);
  #pragma unroll
  for (int ph = 0; ph < 2; ++ph){
    __syncthreads();
    if (wm == ph){
      float* ob = (float*)smem;            // [jw][m 32][o 64] fp32 = 32 KB
      #pragma unroll
      for (int reg = 0; reg < 16; ++reg){
        const int m = (reg & 3) + 8*(reg >> 2) + 4*h32;
        ob[(jw*32 + m)*64 +      l32] = accO0[reg];
        ob[(jw*32 + m)*64 + 32 + l32] = accO1[reg];
      }
    }
    __syncthreads();
    {
      const int i = tid >> 4, o4 = (tid & 15)*4;
      const float* ob = (const float*)smem;
      float4 v0 = *(const float4*)(ob + (0*32 + i)*64 + o4);
      float4 v1 = *(const float4*)(ob + (1*32 + i)*64 + o4);
      float4 v2 = *(const float4*)(ob + (2*32 + i)*64 + o4);
      float4 v3 = *(const float4*)(ob + (3*32 + i)*64 + o4);
      const float l = Lbuf[(ph*4+0)*32 + i] + Lbuf[(ph*4+1)*32 + i]
                    + Lbuf[(ph*4+2)*32 + i] + Lbuf[(ph*4+3)*32 + i];
      const float r = 1.f / l;
      float4 res;
      res.x = (v0.x + v1.x + v2.x + v3.x)*r + bia.x;
      res.y = (v0.y + v1.y + v2.y + v3.y)*r + bia.y;
      res.z = (v0.z + v1.z + v2.z + v3.z)*r + bia.z;
      res.w = (v0.w + v1.w + v2.w + v3.w)*r + bia.w;
      *(float4*)(out + ((size_t)bh*NSEQ + i0 + ph*32 + i)*64 + o4) = res;
    }
  }
}

// ---------------------------------------------------------------------------
extern "C" void kernel_launch(void* const* d_in, const int* in_sizes, int n_in,
                              void* d_out, int out_size, void* d_ws, size_t ws_size,
                              hipStream_t stream)
{
  const float* h     = (const float*)d_in[0];
  const float* w     = (const float*)d_in[1];
  const float* a_src = (const float*)d_in[2];
  const float* a_dst = (const float*)d_in[3];
  const float* bias  = (const float*)d_in[4];
  float* out = (float*)d_out;

  char* ws = (char*)d_ws;
  unsigned short* hpz2 = (unsigned short*)ws;                 // 4 MB bf16 chunk-linear
  float* srcv = (float*)(ws + (4u<<20));                      // 128 KB (log2-scaled)
  float* dstv = (float*)(ws + (4u<<20) + (128u<<10));         // 128 KB (log2-scaled)
  unsigned short* h_bf = (unsigned short*)(ws + (8u<<20));    // 12.58 MB pre-swizzled
  unsigned short* w_bf = (unsigned short*)(ws + (8u<<20) + 12582912u); // 384 KB

  k_prep<<<1584, 512, 0, stream>>>(h, w, h_bf, w_bf);
  k_hprime<<<512, 512, 0, stream>>>(h_bf, w_bf, a_src, a_dst, hpz2, srcv, dstv);
  k_attn<<<512, 512, 0, stream>>>(hpz2, srcv, dstv, bias, out);
}